// Round 4
// baseline (191.543 us; speedup 1.0000x reference)
//
#include <hip/hip_runtime.h>
#include <hip/hip_bf16.h>
#include <hip/hip_fp16.h>
#include <cstdint>

#define DEVINL __device__ __forceinline__

typedef __attribute__((ext_vector_type(4))) float floatx4;
typedef __attribute__((ext_vector_type(8))) __bf16 bf16x8;
typedef __attribute__((ext_vector_type(4))) _Float16 half4;
typedef __attribute__((ext_vector_type(8))) _Float16 half8;
typedef __attribute__((ext_vector_type(4))) unsigned short u16x4;

DEVINL floatx4 mfma_16x16x32(bf16x8 a, bf16x8 b, floatx4 c) {
  return __builtin_amdgcn_mfma_f32_16x16x32_bf16(a, b, c, 0, 0, 0);
}
DEVINL floatx4 mfma_16x16x16_f16(half4 a, half4 b, floatx4 c) {
  return __builtin_amdgcn_mfma_f32_16x16x16f16(a, b, c, 0, 0, 0);
}

// async global->LDS, 16B per lane. LDS dest must be wave-uniform base + lane*16.
DEVINL void async_copy16(const void* g, void* l) {
  __builtin_amdgcn_global_load_lds(
      (__attribute__((address_space(1))) void*)(void*)g,
      (__attribute__((address_space(3))) void*)l, 16, 0, 0);
}

// Q scale: 1/sqrt(64) * log2(e), so softmax can use exp2 (bare v_exp_f32)
#define QSCALE 0.18033688011112042f

// XOR-swizzled fp16 64x64 scratch layout (row d, col s), 8 KB, conflict-light
#define VS(d, s) \
  ((d) * 128 + (((((s) >> 3)) ^ ((d) & 7)) << 4) + ((s) & 7) * 2)

// ---------------------------------------------------------------------------
// prep: one launch does x->bf16 cast (z==4) AND the four 1024x1024 weight
// transpose+casts (z=0..3). Grid (32,32,5), block (32,8).
// ---------------------------------------------------------------------------
__global__ void prep(const float* __restrict__ x, const float* __restrict__ Wq,
                     const float* __restrict__ Wk, const float* __restrict__ Wv,
                     const float* __restrict__ Wo,
                     __hip_bfloat16* __restrict__ xb,
                     __hip_bfloat16* __restrict__ Wt,
                     __hip_bfloat16* __restrict__ Wot) {
  const int z = blockIdx.z;
  const int tx = threadIdx.x, ty = threadIdx.y;  // (32,8)
  if (z == 4) {
    const int bi = blockIdx.y * 32 + blockIdx.x;   // [0,1024)
    const int tid = ty * 32 + tx;                  // [0,256)
    const int base = bi * 4096 + tid * 4;
#pragma unroll
    for (int j = 0; j < 4; ++j) {
      const int i = base + j * 1024;
      const float4 v = *(const float4*)&x[i];
      xb[i + 0] = __float2bfloat16(v.x);
      xb[i + 1] = __float2bfloat16(v.y);
      xb[i + 2] = __float2bfloat16(v.z);
      xb[i + 3] = __float2bfloat16(v.w);
    }
    return;
  }
  __shared__ float tile[32][33];
  const float* W = (z == 0) ? Wq : (z == 1) ? Wk : (z == 2) ? Wv : Wo;
  __hip_bfloat16* dst = (z < 3) ? (Wt + ((int64_t)z << 20)) : Wot;
  const int k0 = blockIdx.x * 32, n0 = blockIdx.y * 32;
#pragma unroll
  for (int i = 0; i < 32; i += 8)
    tile[ty + i][tx] = W[(int64_t)(k0 + ty + i) * 1024 + n0 + tx];
  __syncthreads();
#pragma unroll
  for (int i = 0; i < 32; i += 8)
    dst[(int64_t)(n0 + ty + i) * 1024 + k0 + tx] =
        __float2bfloat16(tile[tx][ty + i]);
}

// ---------------------------------------------------------------------------
// GEMM: C[M][N] = A[M][K] * Bt[N][K]^T  (bf16, MFMA 16x16x32), BK=64,
// XOR-swizzled LDS staging (chunk ^= row&7). TM x TN tile, 256 threads.
// MODE 0 (128x128, OCC=3): QKV epilogue. 768 blocks at 3 blocks/CU are all
//   co-resident in ONE dispatch round. VGPR cap 170 > ~130 live: no spill
//   expected -- canary is WRITE_SIZE (must stay ~24 MB).
// MODE 1 (128x64, OCC=2): plain fp32 store; 512 blocks = 1 round at 2/CU.
// ---------------------------------------------------------------------------
template <int MODE, int TM, int TN, int OCC>
__global__ __launch_bounds__(256, OCC) void gemm_bt(
    const __hip_bfloat16* __restrict__ A, const __hip_bfloat16* __restrict__ Bt,
    int M, int N, int K, const float* __restrict__ bq,
    const float* __restrict__ bk, const float* __restrict__ bv,
    __hip_bfloat16* __restrict__ Qb, __hip_bfloat16* __restrict__ Kb,
    _Float16* __restrict__ Vt, float* __restrict__ outf) {
  constexpr int MI = TM / 32, NJ = TN / 32;  // acc tile dims per wave
  __shared__ __align__(16) char As[TM * 128];  // TM rows x 64 bf16
  __shared__ __align__(16) char Bs[TN * 128];
  const int tid = threadIdx.x;
  const int wave = tid >> 6, lane = tid & 63;
  const int quad = lane >> 4, l16 = lane & 15;
  const int bm = blockIdx.x * TM, bn = blockIdx.y * TN;
  const int wm = (wave >> 1) * (TM / 2), wn = (wave & 1) * (TN / 2);
  const int sw = l16 & 7;

  floatx4 acc[MI][NJ] = {};

  for (int k0 = 0; k0 < K; k0 += 64) {
#pragma unroll
    for (int i = 0; i < TM / 32; ++i) {
      const int p = tid + i * 256;
      const int r = p >> 3, cc = (p & 7) ^ (r & 7);
      async_copy16(A + (int64_t)(bm + r) * K + k0 + cc * 8, As + p * 16);
    }
#pragma unroll
    for (int i = 0; i < TN / 32; ++i) {
      const int p = tid + i * 256;
      const int r = p >> 3, cc = (p & 7) ^ (r & 7);
      async_copy16(Bt + (int64_t)(bn + r) * K + k0 + cc * 8, Bs + p * 16);
    }
    __syncthreads();
    bf16x8 af[MI][2], bfr[NJ][2];
#pragma unroll
    for (int i = 0; i < MI; ++i)
#pragma unroll
      for (int h = 0; h < 2; ++h)
        af[i][h] = *(const bf16x8*)(As + (wm + i * 16 + l16) * 128 +
                                    (((h * 4 + quad) ^ sw) << 4));
#pragma unroll
    for (int j = 0; j < NJ; ++j)
#pragma unroll
      for (int h = 0; h < 2; ++h)
        bfr[j][h] = *(const bf16x8*)(Bs + (wn + j * 16 + l16) * 128 +
                                     (((h * 4 + quad) ^ sw) << 4));
#pragma unroll
    for (int i = 0; i < MI; ++i)
#pragma unroll
      for (int j = 0; j < NJ; ++j)
#pragma unroll
        for (int h = 0; h < 2; ++h)
          acc[i][j] = mfma_16x16x32(af[i][h], bfr[j][h], acc[i][j]);
    __syncthreads();
  }

  if (MODE == 1) {
#pragma unroll
    for (int i = 0; i < MI; ++i)
#pragma unroll
      for (int j = 0; j < NJ; ++j) {
        const int n = bn + wn + j * 16 + l16;
#pragma unroll
        for (int r = 0; r < 4; ++r) {
          const int m = bm + wm + i * 16 + quad * 4 + r;
          outf[(int64_t)m * N + n] = acc[i][j][r];
        }
      }
  } else if (bn < 2048) {
    // ---- Q / K epilogue: bias (+QSCALE for Q), bf16 [B,H,S,64] ----
#pragma unroll
    for (int i = 0; i < MI; ++i)
#pragma unroll
      for (int j = 0; j < NJ; ++j) {
        const int n = bn + wn + j * 16 + l16;
        const int which = n >> 10, nn = n & 1023;
        const int h = nn >> 6, d = nn & 63;
        const float* bias = (which == 0) ? bq : bk;
#pragma unroll
        for (int r = 0; r < 4; ++r) {
          const int m = bm + wm + i * 16 + quad * 4 + r;
          const int b = m >> 11, s = m & 2047;
          float v = acc[i][j][r] + bias[nn];
          if (which == 0) v *= QSCALE;
          ((which == 0) ? Qb : Kb)[((int64_t)(b * 16 + h) * 2048 + s) * 64 + d] =
              __float2bfloat16(v);
        }
      }
  } else {
    // ---- V epilogue: LDS transpose -> Vt[B,H,64,S], coalesced rows ----
    char* scr = (wave & 1) ? Bs : As;  // >=8 KB per wave
    const int h = ((bn + wn) & 1023) >> 6;
    const int bb = (bm + wm) >> 11;
    const int sbase = (bm + wm) & 2047;
    _Float16* dstV = Vt + (int64_t)(bb * 16 + h) * 64 * 2048;
#pragma unroll
    for (int phase = 0; phase < 2; ++phase) {
      __syncthreads();
      if ((wave >> 1) == phase) {
#pragma unroll
        for (int i = 0; i < 4; ++i)
#pragma unroll
          for (int j = 0; j < 4; ++j) {
            const int d = j * 16 + l16;
#pragma unroll
            for (int r = 0; r < 4; ++r) {
              const int s = i * 16 + quad * 4 + r;
              *(_Float16*)(scr + VS(d, s)) =
                  (_Float16)(acc[i][j][r] + bv[((bn + wn) & 1023) + d]);
            }
          }
      }
      __syncthreads();
      if ((wave >> 1) == phase) {
#pragma unroll
        for (int it = 0; it < 8; ++it) {
          const int idx = lane + it * 64;  // [0,512)
          const int d = idx >> 3, sc = idx & 7;
          const half8 vv =
              *(const half8*)(scr + d * 128 + ((sc ^ (d & 7)) << 4));
          *(half8*)(dstV + (int64_t)d * 2048 + sbase + sc * 8) = vv;
        }
      }
    }
  }
}

// ---------------------------------------------------------------------------
// Flash attention v16: k-split waves + PER-WAVE DMA double-buffer.
// Round-3 post-mortem: v15's direct global->reg K/V loads were the
// regression (65.8 us): each vfr load touches 16 distinct 32B segments ->
// ~384 L2 requests/tile/wave vs 16 coalesced global_load_lds. Fix: keep the
// k-split (8 serial tiles/wave, no lock-step), but each wave stages K/V
// into its OWN 2x16KB LDS buffers with global_load_lds and paces itself
// with counted s_waitcnt vmcnt(16) (stage(t+1) is always the newest 16
// outstanding VMEM ops at tile t's wait, so vmcnt(16) retires stage(t)
// regardless of where the Q loads got scheduled). Restage of buf[t&1] only
// after lgkmcnt(0) drains the fragment ds_reads. ZERO __syncthreads in the
// main loop. LDS 128KB -> 1 block/CU (4 waves); per-tile compute ~1300 cyc
// covers L2 latency at prefetch distance 1. Combine: barrier, write O^T/l
// partials into reused staging LDS, barrier, cross-wave fp32 reduce, store.
// ---------------------------------------------------------------------------
__global__ __launch_bounds__(256, 1) void attn_kernel(
    const __hip_bfloat16* __restrict__ Qb, const __hip_bfloat16* __restrict__ Kb,
    const _Float16* __restrict__ Vt, __hip_bfloat16* __restrict__ Ab) {
  // per wave 32KB: buf b at wave*32K + b*16K  (K 8KB bf16 | V 8KB fp16)
  // combine reuses [0, 69632) after a barrier.
  __shared__ __align__(16) char smem[131072];
  const int tid = threadIdx.x;
  const int wave = tid >> 6, lane = tid & 63;
  const int quad = lane >> 4, l16 = lane & 15;
  const int c = 31 - (int)(blockIdx.x >> 5);  // long chunks dispatch first
  const int bh = blockIdx.x & 31;
  const int qbase = c * 64;

  const __hip_bfloat16* Qh = Qb + (int64_t)bh * 2048 * 64;
  const __hip_bfloat16* Kh = Kb + (int64_t)bh * 2048 * 64;
  const _Float16* Vh = Vt + (int64_t)bh * 64 * 2048;

  // Q B-fragments for all 4 q-subtiles of this chunk (held in regs)
  bf16x8 qf[4][2];
#pragma unroll
  for (int qc = 0; qc < 4; ++qc)
#pragma unroll
    for (int h = 0; h < 2; ++h)
      qf[qc][h] = *(const bf16x8*)&Qh[(int64_t)(qbase + qc * 16 + l16) * 64 +
                                      h * 32 + quad * 8];

  floatx4 o[4][4] = {};  // [dt][qc]  O^T: row d = dt*16+quad*4+r, col = l16
  float ls[4] = {};      // lsum partial per qc

  char* const wbase = smem + wave * 32768;

  // stage one 64-key tile (K 8KB + V 8KB) into per-wave buf: 16 VMEM ops
  auto stage = [&](int buf, int k0s) {
    char* kb = wbase + buf * 16384;
#pragma unroll
    for (int i = 0; i < 8; ++i) {
      const int p = lane + i * 64;
      const int r = p >> 3, cc = (p & 7) ^ (r & 7);
      async_copy16(Kh + (int64_t)(k0s + r) * 64 + cc * 8, kb + p * 16);
    }
#pragma unroll
    for (int i = 0; i < 8; ++i) {
      const int p = lane + i * 64;
      const int r = p >> 3, cc = (p & 7) ^ (r & 7);
      async_copy16(Vh + (int64_t)r * 2048 + k0s + cc * 8, kb + 8192 + p * 16);
    }
  };

  const int nt = (c >= wave) ? ((c - wave) >> 2) + 1 : 0;
  if (nt > 0) stage(0, wave * 64);
  if (nt > 1) stage(1, (wave + 4) * 64);

  for (int t = 0; t < nt; ++t) {
    const int kt = wave + t * 4;
    const int k0 = kt * 64;
    // pace: retire everything older than stage(t+1) => stage(t) complete
    if (t + 1 < nt) {
      asm volatile("s_waitcnt vmcnt(16)" ::: "memory");
    } else {
      asm volatile("s_waitcnt vmcnt(0)" ::: "memory");
    }
    const char* kb = wbase + (t & 1) * 16384;
    const char* vb = kb + 8192;
    const int sw = l16 & 7;

    bf16x8 kfr[4][2];
#pragma unroll
    for (int kk = 0; kk < 4; ++kk)
#pragma unroll
      for (int h = 0; h < 2; ++h)
        kfr[kk][h] = *(const bf16x8*)(kb + (kk * 16 + l16) * 128 +
                                      (((h * 4 + quad) ^ sw) << 4));
    half4 vfr[4][4];
#pragma unroll
    for (int dt = 0; dt < 4; ++dt)
#pragma unroll
      for (int kk = 0; kk < 4; ++kk)
        vfr[dt][kk] = *(const half4*)(vb + (dt * 16 + l16) * 128 +
                                      (((kk * 2 + (quad >> 1)) ^ sw) << 4) +
                                      (quad & 1) * 8);
    // frags now being read into regs; drain before overwriting this buffer
    asm volatile("s_waitcnt lgkmcnt(0)" ::: "memory");
    if (t + 2 < nt) stage(t & 1, (kt + 8) * 64);

    const bool diag = (kt == c);
#pragma unroll
    for (int qc = 0; qc < 4; ++qc) {
      // S^T = K Q^T : C holds S^T[key=quad*4+r][qrow=l16]
      floatx4 st[4];
#pragma unroll
      for (int kk = 0; kk < 4; ++kk) {
        floatx4 z = {};
        z = mfma_16x16x32(kfr[kk][0], qf[qc][0], z);
        st[kk] = mfma_16x16x32(kfr[kk][1], qf[qc][1], z);
      }
      // P = exp2(S), causal mask on diagonal tile; pack fp16
      half4 pf[4];
#pragma unroll
      for (int kk = 0; kk < 4; ++kk) {
#pragma unroll
        for (int r = 0; r < 4; ++r) {
          const int key = k0 + kk * 16 + quad * 4 + r;
          float p = __builtin_amdgcn_exp2f(st[kk][r]);
          if (diag && key > qbase + qc * 16 + l16) p = 0.f;
          ls[qc] += p;
          pf[kk][r] = (_Float16)p;
        }
      }
      // O^T += V^T P^T
#pragma unroll
      for (int dt = 0; dt < 4; ++dt)
#pragma unroll
        for (int kk = 0; kk < 4; ++kk)
          o[dt][qc] = mfma_16x16x16_f16(vfr[dt][kk], pf[kk], o[dt][qc]);
    }
  }

  // -------- combine: all waves done; reuse staging LDS as scratch --------
  __syncthreads();
  {
    char* ob = smem + wave * 17408;
#pragma unroll
    for (int dt = 0; dt < 4; ++dt)
#pragma unroll
      for (int qc = 0; qc < 4; ++qc)
        *(floatx4*)(ob + (dt * 4 + qc) * 1024 + lane * 16) = o[dt][qc];
    float* lsb = (float*)(ob + 16384);
#pragma unroll
    for (int qc = 0; qc < 4; ++qc) lsb[qc * 64 + lane] = ls[qc];
  }
  __syncthreads();

  const int dt = wave;  // each wave finalizes one 16-row d-tile
  const int b = bh >> 4, h = bh & 15;
#pragma unroll
  for (int qc = 0; qc < 4; ++qc) {
    floatx4 s = {};
    float lt = 0.f;
#pragma unroll
    for (int w = 0; w < 4; ++w) {
      s += *(const floatx4*)(smem + w * 17408 + (dt * 4 + qc) * 1024 +
                             lane * 16);
      lt += ((const float*)(smem + w * 17408 + 16384))[qc * 64 + lane];
    }
    lt += __shfl_xor(lt, 16, 64);
    lt += __shfl_xor(lt, 32, 64);
    const float inv = 1.0f / lt;
    u16x4 pack;
#pragma unroll
    for (int r = 0; r < 4; ++r)
      pack[r] = __builtin_bit_cast(unsigned short,
                                   __float2bfloat16(s[r] * inv));
    *(u16x4*)&Ab[(int64_t)(b * 2048 + qbase + qc * 16 + l16) * 1024 + h * 64 +
                 dt * 16 + quad * 4] = pack;
  }
}

// ---------------------------------------------------------------------------
// Workspace layout (bytes), needs 40 MB:
//   [0,  8M): xb  (x as bf16, 4096x1024)  -- reused as Ab (attn out) later
//   [8, 14M): Wt  (Wq|Wk|Wv transposed bf16, 3072x1024)
//   [14,16M): Wot (Wo transposed bf16, 1024x1024)
//   [16,24M): Qb  [B,H,S,64] bf16 (pre-scaled by QSCALE)
//   [24,32M): Kb  [B,H,S,64] bf16
//   [32,40M): Vt  [B,H,64,S] fp16 (written directly by gemm_bt<0> epilogue)
// ---------------------------------------------------------------------------
extern "C" void kernel_launch(void* const* d_in, const int* in_sizes, int n_in,
                              void* d_out, int out_size, void* d_ws,
                              size_t ws_size, hipStream_t stream) {
  const float* x = (const float*)d_in[0];
  const float* Wq = (const float*)d_in[1];
  const float* bq = (const float*)d_in[2];
  const float* Wk = (const float*)d_in[3];
  const float* bk = (const float*)d_in[4];
  const float* Wv = (const float*)d_in[5];
  const float* bv = (const float*)d_in[6];
  const float* Wo = (const float*)d_in[7];
  float* out = (float*)d_out;

  char* ws = (char*)d_ws;
  __hip_bfloat16* xb = (__hip_bfloat16*)(ws);
  __hip_bfloat16* Wt = (__hip_bfloat16*)(ws + (8ll << 20));
  __hip_bfloat16* Wot = (__hip_bfloat16*)(ws + (14ll << 20));
  __hip_bfloat16* Qb = (__hip_bfloat16*)(ws + (16ll << 20));
  __hip_bfloat16* Kb = (__hip_bfloat16*)(ws + (24ll << 20));
  _Float16* Vt = (_Float16*)(ws + (32ll << 20));
  __hip_bfloat16* Ab = xb;  // x dead after QKV GEMM

  prep<<<dim3(32, 32, 5), dim3(32, 8), 0, stream>>>(x, Wq, Wk, Wv, Wo, xb, Wt,
                                                    Wot);
  gemm_bt<0, 128, 128, 3><<<dim3(32, 24), 256, 0, stream>>>(
      xb, Wt, 4096, 3072, 1024, bq, bk, bv, Qb, Kb, Vt, nullptr);
  attn_kernel<<<dim3(1024), 256, 0, stream>>>(Qb, Kb, Vt, Ab);
  gemm_bt<1, 128, 64, 2><<<dim3(32, 16), 256, 0, stream>>>(
      Ab, Wot, 4096, 1024, 1024, nullptr, nullptr, nullptr, nullptr, nullptr,
      nullptr, out);
}

// Round 5
// 170.777 us; speedup vs baseline: 1.1216x; 1.1216x over previous
//
#include <hip/hip_runtime.h>
#include <hip/hip_bf16.h>
#include <hip/hip_fp16.h>
#include <cstdint>

#define DEVINL __device__ __forceinline__

typedef __attribute__((ext_vector_type(4))) float floatx4;
typedef __attribute__((ext_vector_type(8))) __bf16 bf16x8;
typedef __attribute__((ext_vector_type(4))) _Float16 half4;
typedef __attribute__((ext_vector_type(8))) _Float16 half8;
typedef __attribute__((ext_vector_type(4))) unsigned short u16x4;

DEVINL floatx4 mfma_16x16x32(bf16x8 a, bf16x8 b, floatx4 c) {
  return __builtin_amdgcn_mfma_f32_16x16x32_bf16(a, b, c, 0, 0, 0);
}
DEVINL floatx4 mfma_16x16x16_f16(half4 a, half4 b, floatx4 c) {
  return __builtin_amdgcn_mfma_f32_16x16x16f16(a, b, c, 0, 0, 0);
}

// async global->LDS, 16B per lane. LDS dest must be wave-uniform base + lane*16.
DEVINL void async_copy16(const void* g, void* l) {
  __builtin_amdgcn_global_load_lds(
      (__attribute__((address_space(1))) void*)(void*)g,
      (__attribute__((address_space(3))) void*)l, 16, 0, 0);
}

// Q scale: 1/sqrt(64) * log2(e), so softmax can use exp2 (bare v_exp_f32)
#define QSCALE 0.18033688011112042f

// XOR-swizzled fp16 64x64 scratch layout (row d, col s), 8 KB, conflict-light
#define VS(d, s) \
  ((d) * 128 + (((((s) >> 3)) ^ ((d) & 7)) << 4) + ((s) & 7) * 2)

// ---------------------------------------------------------------------------
// prep: one launch does x->bf16 cast (z==4) AND the four 1024x1024 weight
// transpose+casts (z=0..3). Grid (32,32,5), block (32,8).
// ---------------------------------------------------------------------------
__global__ void prep(const float* __restrict__ x, const float* __restrict__ Wq,
                     const float* __restrict__ Wk, const float* __restrict__ Wv,
                     const float* __restrict__ Wo,
                     __hip_bfloat16* __restrict__ xb,
                     __hip_bfloat16* __restrict__ Wt,
                     __hip_bfloat16* __restrict__ Wot) {
  const int z = blockIdx.z;
  const int tx = threadIdx.x, ty = threadIdx.y;  // (32,8)
  if (z == 4) {
    const int bi = blockIdx.y * 32 + blockIdx.x;   // [0,1024)
    const int tid = ty * 32 + tx;                  // [0,256)
    const int base = bi * 4096 + tid * 4;
#pragma unroll
    for (int j = 0; j < 4; ++j) {
      const int i = base + j * 1024;
      const float4 v = *(const float4*)&x[i];
      xb[i + 0] = __float2bfloat16(v.x);
      xb[i + 1] = __float2bfloat16(v.y);
      xb[i + 2] = __float2bfloat16(v.z);
      xb[i + 3] = __float2bfloat16(v.w);
    }
    return;
  }
  __shared__ float tile[32][33];
  const float* W = (z == 0) ? Wq : (z == 1) ? Wk : (z == 2) ? Wv : Wo;
  __hip_bfloat16* dst = (z < 3) ? (Wt + ((int64_t)z << 20)) : Wot;
  const int k0 = blockIdx.x * 32, n0 = blockIdx.y * 32;
#pragma unroll
  for (int i = 0; i < 32; i += 8)
    tile[ty + i][tx] = W[(int64_t)(k0 + ty + i) * 1024 + n0 + tx];
  __syncthreads();
#pragma unroll
  for (int i = 0; i < 32; i += 8)
    dst[(int64_t)(n0 + ty + i) * 1024 + k0 + tx] =
        __float2bfloat16(tile[tx][ty + i]);
}

// ---------------------------------------------------------------------------
// GEMM: C[M][N] = A[M][K] * Bt[N][K]^T  (bf16, MFMA 16x16x32), BK=64,
// XOR-swizzled LDS staging (chunk ^= row&7). TM x TN tile, 256 threads.
// MODE 0 (128x128, OCC=3): QKV epilogue. 768 blocks at 3 blocks/CU are all
//   co-resident in ONE dispatch round. VGPR cap 170 > ~130 live: no spill
//   expected -- canary is WRITE_SIZE (must stay ~24 MB).
// MODE 1 (128x64, OCC=2): plain fp32 store; 512 blocks = 1 round at 2/CU.
// ---------------------------------------------------------------------------
template <int MODE, int TM, int TN, int OCC>
__global__ __launch_bounds__(256, OCC) void gemm_bt(
    const __hip_bfloat16* __restrict__ A, const __hip_bfloat16* __restrict__ Bt,
    int M, int N, int K, const float* __restrict__ bq,
    const float* __restrict__ bk, const float* __restrict__ bv,
    __hip_bfloat16* __restrict__ Qb, __hip_bfloat16* __restrict__ Kb,
    _Float16* __restrict__ Vt, float* __restrict__ outf) {
  constexpr int MI = TM / 32, NJ = TN / 32;  // acc tile dims per wave
  __shared__ __align__(16) char As[TM * 128];  // TM rows x 64 bf16
  __shared__ __align__(16) char Bs[TN * 128];
  const int tid = threadIdx.x;
  const int wave = tid >> 6, lane = tid & 63;
  const int quad = lane >> 4, l16 = lane & 15;
  const int bm = blockIdx.x * TM, bn = blockIdx.y * TN;
  const int wm = (wave >> 1) * (TM / 2), wn = (wave & 1) * (TN / 2);
  const int sw = l16 & 7;

  floatx4 acc[MI][NJ] = {};

  for (int k0 = 0; k0 < K; k0 += 64) {
#pragma unroll
    for (int i = 0; i < TM / 32; ++i) {
      const int p = tid + i * 256;
      const int r = p >> 3, cc = (p & 7) ^ (r & 7);
      async_copy16(A + (int64_t)(bm + r) * K + k0 + cc * 8, As + p * 16);
    }
#pragma unroll
    for (int i = 0; i < TN / 32; ++i) {
      const int p = tid + i * 256;
      const int r = p >> 3, cc = (p & 7) ^ (r & 7);
      async_copy16(Bt + (int64_t)(bn + r) * K + k0 + cc * 8, Bs + p * 16);
    }
    __syncthreads();
    bf16x8 af[MI][2], bfr[NJ][2];
#pragma unroll
    for (int i = 0; i < MI; ++i)
#pragma unroll
      for (int h = 0; h < 2; ++h)
        af[i][h] = *(const bf16x8*)(As + (wm + i * 16 + l16) * 128 +
                                    (((h * 4 + quad) ^ sw) << 4));
#pragma unroll
    for (int j = 0; j < NJ; ++j)
#pragma unroll
      for (int h = 0; h < 2; ++h)
        bfr[j][h] = *(const bf16x8*)(Bs + (wn + j * 16 + l16) * 128 +
                                     (((h * 4 + quad) ^ sw) << 4));
#pragma unroll
    for (int i = 0; i < MI; ++i)
#pragma unroll
      for (int j = 0; j < NJ; ++j)
#pragma unroll
        for (int h = 0; h < 2; ++h)
          acc[i][j] = mfma_16x16x32(af[i][h], bfr[j][h], acc[i][j]);
    __syncthreads();
  }

  if (MODE == 1) {
#pragma unroll
    for (int i = 0; i < MI; ++i)
#pragma unroll
      for (int j = 0; j < NJ; ++j) {
        const int n = bn + wn + j * 16 + l16;
#pragma unroll
        for (int r = 0; r < 4; ++r) {
          const int m = bm + wm + i * 16 + quad * 4 + r;
          outf[(int64_t)m * N + n] = acc[i][j][r];
        }
      }
  } else if (bn < 2048) {
    // ---- Q / K epilogue: bias (+QSCALE for Q), bf16 [B,H,S,64] ----
#pragma unroll
    for (int i = 0; i < MI; ++i)
#pragma unroll
      for (int j = 0; j < NJ; ++j) {
        const int n = bn + wn + j * 16 + l16;
        const int which = n >> 10, nn = n & 1023;
        const int h = nn >> 6, d = nn & 63;
        const float* bias = (which == 0) ? bq : bk;
#pragma unroll
        for (int r = 0; r < 4; ++r) {
          const int m = bm + wm + i * 16 + quad * 4 + r;
          const int b = m >> 11, s = m & 2047;
          float v = acc[i][j][r] + bias[nn];
          if (which == 0) v *= QSCALE;
          ((which == 0) ? Qb : Kb)[((int64_t)(b * 16 + h) * 2048 + s) * 64 + d] =
              __float2bfloat16(v);
        }
      }
  } else {
    // ---- V epilogue: LDS transpose -> Vt[B,H,64,S], coalesced rows ----
    char* scr = (wave & 1) ? Bs : As;  // >=8 KB per wave
    const int h = ((bn + wn) & 1023) >> 6;
    const int bb = (bm + wm) >> 11;
    const int sbase = (bm + wm) & 2047;
    _Float16* dstV = Vt + (int64_t)(bb * 16 + h) * 64 * 2048;
#pragma unroll
    for (int phase = 0; phase < 2; ++phase) {
      __syncthreads();
      if ((wave >> 1) == phase) {
#pragma unroll
        for (int i = 0; i < 4; ++i)
#pragma unroll
          for (int j = 0; j < 4; ++j) {
            const int d = j * 16 + l16;
#pragma unroll
            for (int r = 0; r < 4; ++r) {
              const int s = i * 16 + quad * 4 + r;
              *(_Float16*)(scr + VS(d, s)) =
                  (_Float16)(acc[i][j][r] + bv[((bn + wn) & 1023) + d]);
            }
          }
      }
      __syncthreads();
      if ((wave >> 1) == phase) {
#pragma unroll
        for (int it = 0; it < 8; ++it) {
          const int idx = lane + it * 64;  // [0,512)
          const int d = idx >> 3, sc = idx & 7;
          const half8 vv =
              *(const half8*)(scr + d * 128 + ((sc ^ (d & 7)) << 4));
          *(half8*)(dstV + (int64_t)d * 2048 + sbase + sc * 8) = vv;
        }
      }
    }
  }
}

// ---------------------------------------------------------------------------
// Flash attention v17 = v13 (the proven lockstep 4-wave shape, ~38-42 us)
// + T3/T4-lite: TRIPLE-buffered K/V staging with counted s_waitcnt vmcnt(4)
// and raw s_barrier instead of __syncthreads.
// Post-mortems r1-r4: v13 is mostly throughput-bound WITH 3-way block
// co-residency hiding latency (k-split variants that dropped occupancy to
// 1-2 blk/CU regressed to 57-66 us). The remaining v13 stall is the
// __syncthreads implicit vmcnt(0) drain: it waits on the prefetch issued
// only ~800 cyc earlier and stalls all 4 waves together. With 3 buffers,
// stage(t+2) is issued right after the barrier (overwriting buf[(t-1)%3],
// whose reads all retired before any wave reached this barrier -- every
// read's MFMA consumer executed in iter t-1), and the per-iter wait is
// vmcnt(4): outstanding = stage(t) 4/thread + stage(t+1) 4/thread, so
// vmcnt(4) retires stage(t) while stage(t+1) flies ACROSS the barrier.
// vmcnt(0) only on the final (diagonal) tile. Prefetch cover ~800->1900cyc.
// LDS 48KB -> still 3 blocks/CU (144 <= 160 KB).
// ---------------------------------------------------------------------------
__global__ __launch_bounds__(256, 3) void attn_kernel(
    const __hip_bfloat16* __restrict__ Qb, const __hip_bfloat16* __restrict__ Kb,
    const _Float16* __restrict__ Vt, __hip_bfloat16* __restrict__ Ab) {
  // 3 bufs x 16KB: [b*16K, b*16K+8K) = K bf16 64x64 ; [+8K, +16K) = V fp16
  __shared__ __align__(16) char smem[49152];
  const int tid = threadIdx.x;
  const int wave = tid >> 6, lane = tid & 63;
  const int quad = lane >> 4, l16 = lane & 15;
  const int c = 31 - (int)(blockIdx.x >> 5);  // long chunks dispatch first
  const int bh = blockIdx.x & 31;
  const int qbase = c * 64 + wave * 16;  // this wave's 16 Q rows
  const int ktmax = c;                   // uniform across waves

  const __hip_bfloat16* Qh = Qb + (int64_t)bh * 2048 * 64;
  const __hip_bfloat16* Kh = Kb + (int64_t)bh * 2048 * 64;
  const _Float16* Vh = Vt + (int64_t)bh * 64 * 2048;

  // Q B-fragments (16x16x32): Q[qrow=l16][d=h*32+quad*8+j]
  bf16x8 qf[2];
#pragma unroll
  for (int h = 0; h < 2; ++h)
    qf[h] = *(const bf16x8*)&Qh[(int64_t)(qbase + l16) * 64 + h * 32 + quad * 8];

  floatx4 o[4] = {};  // O^T[dt][C: row=d(quad*4+r), col=qrow(l16)]
  float lsum = 0.f;

  auto stage = [&](int buf, int k0s) {
#pragma unroll
    for (int i = 0; i < 2; ++i) {
      const int p = tid + i * 256;  // [0,512)
      const int r = p >> 3, cc = (p & 7) ^ (r & 7);
      async_copy16(Kh + (int64_t)(k0s + r) * 64 + cc * 8,
                   smem + buf * 16384 + p * 16);
      async_copy16(Vh + (int64_t)r * 2048 + k0s + cc * 8,
                   smem + buf * 16384 + 8192 + p * 16);
    }
  };

  stage(0, 0);
  if (ktmax >= 1) stage(1, 64);
  int cur = 0;
  for (int kt = 0; kt <= ktmax; ++kt) {
    const int k0 = kt * 64;
    // counted wait: newest 4/thread outstanding = stage(kt+1); everything
    // older (incl. stage(kt) and the qf loads) retires. Never 0 mid-loop.
    if (kt < ktmax) {
      asm volatile("s_waitcnt vmcnt(4)" ::: "memory");
    } else {
      asm volatile("s_waitcnt vmcnt(0)" ::: "memory");
    }
    __builtin_amdgcn_s_barrier();
    // prefetch kt+2 into buf[(cur+2)%3] (= buffer read at kt-1; all waves'
    // reads of it retired before they reached the barrier above)
    if (kt + 2 <= ktmax) stage(cur == 0 ? 2 : cur - 1, k0 + 128);

    const char* kb = smem + cur * 16384;
    const char* vb = kb + 8192;
    const int sw = l16 & 7;

    bf16x8 kfr[4][2];
#pragma unroll
    for (int kk = 0; kk < 4; ++kk)
#pragma unroll
      for (int h = 0; h < 2; ++h)
        kfr[kk][h] = *(const bf16x8*)(kb + (kk * 16 + l16) * 128 +
                                      (((h * 4 + quad) ^ sw) << 4));

    // S^T = K Q^T : C holds S^T[key=quad*4+r][qrow=l16]
    floatx4 st[4];
#pragma unroll
    for (int kk = 0; kk < 4; ++kk) {
      floatx4 z = {};
      z = mfma_16x16x32(kfr[kk][0], qf[0], z);
      st[kk] = mfma_16x16x32(kfr[kk][1], qf[1], z);
    }

    half4 vfr[4][4];
#pragma unroll
    for (int dt = 0; dt < 4; ++dt)
#pragma unroll
      for (int kk = 0; kk < 4; ++kk)
        vfr[dt][kk] = *(const half4*)(vb + (dt * 16 + l16) * 128 +
                                      (((kk * 2 + (quad >> 1)) ^ sw) << 4) +
                                      (quad & 1) * 8);

    // P = exp2(S), causal mask on diagonal tile; pack fp16 (B-operand layout)
    const bool masked = (kt == ktmax);
    half4 pf[4];
#pragma unroll
    for (int kk = 0; kk < 4; ++kk) {
#pragma unroll
      for (int r = 0; r < 4; ++r) {
        const int key = k0 + kk * 16 + quad * 4 + r;
        float p = __builtin_amdgcn_exp2f(st[kk][r]);
        if (masked && key > qbase + l16) p = 0.f;
        lsum += p;
        pf[kk][r] = (_Float16)p;
      }
    }

    // O^T += V^T P^T
#pragma unroll
    for (int dt = 0; dt < 4; ++dt)
#pragma unroll
      for (int kk = 0; kk < 4; ++kk)
        o[dt] = mfma_16x16x16_f16(vfr[dt][kk], pf[kk], o[dt]);

    cur = (cur == 2) ? 0 : cur + 1;
  }

  // ---- finalize: l is split across the 4 quads per qrow; reduce ----
  lsum += __shfl_xor(lsum, 16, 64);
  lsum += __shfl_xor(lsum, 32, 64);
  const float invl = 1.0f / lsum;

  // store bf16 [B,S,H*64]: row = qbase+l16, cols h*64 + dt*16 + quad*4 + r
  const int b = bh >> 4, h = bh & 15;
#pragma unroll
  for (int dt = 0; dt < 4; ++dt) {
    u16x4 pack;
#pragma unroll
    for (int r = 0; r < 4; ++r)
      pack[r] = __builtin_bit_cast(unsigned short,
                                   __float2bfloat16(o[dt][r] * invl));
    *(u16x4*)&Ab[(int64_t)(b * 2048 + qbase + l16) * 1024 + h * 64 + dt * 16 +
                 quad * 4] = pack;
  }
}

// ---------------------------------------------------------------------------
// Workspace layout (bytes), needs 40 MB:
//   [0,  8M): xb  (x as bf16, 4096x1024)  -- reused as Ab (attn out) later
//   [8, 14M): Wt  (Wq|Wk|Wv transposed bf16, 3072x1024)
//   [14,16M): Wot (Wo transposed bf16, 1024x1024)
//   [16,24M): Qb  [B,H,S,64] bf16 (pre-scaled by QSCALE)
//   [24,32M): Kb  [B,H,S,64] bf16
//   [32,40M): Vt  [B,H,64,S] fp16 (written directly by gemm_bt<0> epilogue)
// ---------------------------------------------------------------------------
extern "C" void kernel_launch(void* const* d_in, const int* in_sizes, int n_in,
                              void* d_out, int out_size, void* d_ws,
                              size_t ws_size, hipStream_t stream) {
  const float* x = (const float*)d_in[0];
  const float* Wq = (const float*)d_in[1];
  const float* bq = (const float*)d_in[2];
  const float* Wk = (const float*)d_in[3];
  const float* bk = (const float*)d_in[4];
  const float* Wv = (const float*)d_in[5];
  const float* bv = (const float*)d_in[6];
  const float* Wo = (const float*)d_in[7];
  float* out = (float*)d_out;

  char* ws = (char*)d_ws;
  __hip_bfloat16* xb = (__hip_bfloat16*)(ws);
  __hip_bfloat16* Wt = (__hip_bfloat16*)(ws + (8ll << 20));
  __hip_bfloat16* Wot = (__hip_bfloat16*)(ws + (14ll << 20));
  __hip_bfloat16* Qb = (__hip_bfloat16*)(ws + (16ll << 20));
  __hip_bfloat16* Kb = (__hip_bfloat16*)(ws + (24ll << 20));
  _Float16* Vt = (_Float16*)(ws + (32ll << 20));
  __hip_bfloat16* Ab = xb;  // x dead after QKV GEMM

  prep<<<dim3(32, 32, 5), dim3(32, 8), 0, stream>>>(x, Wq, Wk, Wv, Wo, xb, Wt,
                                                    Wot);
  gemm_bt<0, 128, 128, 3><<<dim3(32, 24), 256, 0, stream>>>(
      xb, Wt, 4096, 3072, 1024, bq, bk, bv, Qb, Kb, Vt, nullptr);
  attn_kernel<<<dim3(1024), 256, 0, stream>>>(Qb, Kb, Vt, Ab);
  gemm_bt<1, 128, 64, 2><<<dim3(32, 16), 256, 0, stream>>>(
      Ab, Wot, 4096, 1024, 1024, nullptr, nullptr, nullptr, nullptr, nullptr,
      nullptr, out);
}